// Round 8
// baseline (179.225 us; speedup 1.0000x reference)
//
#include <hip/hip_runtime.h>

// PWC-Net correlation (md=4, 81 disps) + leaky_relu(0.1), mean over C=256.
// B=8 C=256 H=96 W=128, f32 in/out.
//
// R8: block = 3 waves (192 thr), wave = one dy of 3-dy group; grid =
// 8(batch==XCD) x 48(h-tiles) x 3(dy-groups) = 1152 blocks (all-resident).
// x1 now loaded GLOBAL->REG per wave (L1-hit, was 25% of LDS reads and
// 32% of LDS writes); x2-only LDS, double-buffered, ONE barrier/chunk.
// f16-pair packing, v_dot2_f32_f16, conflict-free XOR swizzle (b128 reads
// land 8 distinct rows per bank-quad = the 1024B/128B floor).
// R5/R6 lesson: compiler pins ~84 VGPR; design under it (spill sentinel:
// WRITE_SIZE >> 31MB). R7 lesson: small blocks restored occupancy.

#define B_ 8
#define C_ 256
#define H_ 96
#define W_ 128
#define TH 2
#define CC 8
#define NCH (C_ / CC)            // 32 chunks
#define HW (H_ * W_)
#define CHSTRIDE (CC * HW)       // floats, fits u32
#define S2SZ (4 * 544)           // 2176 u32 per buffer (4 staged x2 rows)
#define NTHR 192
#define NT2 544                  // x2 float4-pair staging tasks per chunk

typedef __fp16 h2_t __attribute__((ext_vector_type(2)));
union H2U { unsigned int u; h2_t h; };

__device__ __forceinline__ h2_t u_as_h2(unsigned int u) { H2U x; x.u = u; return x.h; }

__device__ __forceinline__ unsigned int packh2(float a, float b) {
    H2U x; x.h = __builtin_amdgcn_cvt_pkrtz(a, b); return x.u;
}

#if __has_builtin(__builtin_amdgcn_fdot2)
__device__ __forceinline__ float dot2(unsigned int a, unsigned int b, float c) {
    return __builtin_amdgcn_fdot2(u_as_h2(a), u_as_h2(b), c, false);
}
#else
__device__ __forceinline__ float dot2(unsigned int a, unsigned int b, float c) {
    h2_t ha = u_as_h2(a), hb = u_as_h2(b);
    return c + (float)ha[0] * (float)hb[0] + (float)ha[1] * (float)hb[1];
}
#endif

__global__ __attribute__((amdgpu_flat_work_group_size(NTHR, NTHR)))
void corr_kernel(const float* __restrict__ x1, const float* __restrict__ x2,
                 float* __restrict__ out)
{
    __shared__ __align__(16) unsigned int smem[2][S2SZ];   // 17.4 KB

    const int b   = blockIdx.x;       // batch == XCD (x fastest => round-robin)
    const int h0  = blockIdx.y * TH;
    const int dg  = blockIdx.z;       // dy = 3*dg + wid
    const int tid = threadIdx.x;
    const int wid = tid >> 6;         // 0..2
    const int lane = tid & 63;
    const int hr  = lane >> 5;        // 0..1
    const int wq  = lane & 31;        // 32 groups of 4 w pixels

    // ---------------- x2 staging descriptors (3 rounds x 192 threads) ------
    // task u<544: cp=u&3, q=u>>2, g=q%34 (0..33), r=q/34 (0..3).
    // LDS slot for pixel-slot s, ch-pair cp, row r:
    //   r*544 + (s>>3)*32 + (((s&7)^((s>>3)&7)^(r&7))<<2) + cp
    // task covers s=4g..4g+3 -> idx_k = c + ((k^X)<<2).
    unsigned off_[3];
    int cx_[3];                        // c | (X<<16)
    int mval = 0;
    #pragma unroll
    for (int i = 0; i < 3; ++i) {
        const int u = tid + NTHR * i;
        const bool act = (u < NT2);
        const int v = act ? u : 0;
        const int cp = v & 3, q = v >> 2;
        const int g = q % 34, r = q / 34;
        const int h2 = h0 + 3 * dg + r - 4;
        const bool val = act && (h2 >= 0) && (h2 < H_) && (g >= 1) && (g <= 32);
        const int h2c = val ? h2 : 0, gc = val ? g : 1;
        off_[i] = ((unsigned)(b * C_ + 2 * cp) * H_ + (unsigned)h2c) * W_
                + (unsigned)(4 * gc - 4);
        cx_[i] = (r * 544 + (g >> 1) * 32 + cp)
               | (((4 * (g & 1)) ^ ((g >> 1) & 7) ^ (r & 7)) << 16);
        mval |= (int)val << i;
    }

    // x1 base offset: lane's own 4 pixels on row h0+hr (always in range)
    const unsigned o1 = ((unsigned)(b * C_) * H_ + (unsigned)(h0 + hr)) * W_ + 4u * wq;

    // ---------------- compute setup ----------------
    const int row = hr + wid;              // staged x2 row 0..3
    int a2p[6];                            // 12 chunk-invariant addrs, 2x16b
    #pragma unroll
    for (int t = 0; t < 12; t += 2) {
        const int s0 = 4 * wq + t, s1 = s0 + 1;
        const int A0 = row * 544 + (s0 >> 3) * 32
                     + (((s0 & 7) ^ ((s0 >> 3) & 7) ^ row) << 2);
        const int A1 = row * 544 + (s1 >> 3) * 32
                     + (((s1 & 7) ^ ((s1 >> 3) & 7) ^ row) << 2);
        a2p[t >> 1] = A0 | (A1 << 16);
    }

    float acc[4][9];
    #pragma unroll
    for (int p = 0; p < 4; ++p)
        #pragma unroll
        for (int d = 0; d < 9; ++d) acc[p][d] = 0.f;

    auto STAGE = [&](int cc, unsigned int* S2) {
        const unsigned co = (unsigned)cc * (unsigned)CHSTRIDE;
        #pragma unroll
        for (int i = 0; i < 3; ++i) {
            if ((mval >> i) & 1) {
                const float4 A  = *reinterpret_cast<const float4*>(x2 + off_[i] + co);
                const float4 Bv = *reinterpret_cast<const float4*>(x2 + off_[i] + co + HW);
                const int c = cx_[i] & 0xffff;
                const int X = cx_[i] >> 16;
                S2[c + ((0 ^ X) << 2)] = packh2(A.x, Bv.x);
                S2[c + ((1 ^ X) << 2)] = packh2(A.y, Bv.y);
                S2[c + ((2 ^ X) << 2)] = packh2(A.z, Bv.z);
                S2[c + ((3 ^ X) << 2)] = packh2(A.w, Bv.w);
            }
        }
    };

    // One chunk: x1 loads (2 halves, reg-frugal) + stage next + compute.
    auto FULL = [&](int cc, const unsigned int* S2rd, unsigned int* S2wr,
                    bool doStage) {
        const float* p1 = x1 + o1 + (unsigned)cc * (unsigned)CHSTRIDE;
        uint4 x1v[4];
        {   // channels 0..3 (ch-pairs j=0,1)
            const float4 A0 = *reinterpret_cast<const float4*>(p1);
            const float4 B0 = *reinterpret_cast<const float4*>(p1 + HW);
            const float4 A1 = *reinterpret_cast<const float4*>(p1 + 2 * HW);
            const float4 B1 = *reinterpret_cast<const float4*>(p1 + 3 * HW);
            if (doStage) STAGE(cc + 1, S2wr);       // overlap with x1 latency
            x1v[0].x = packh2(A0.x, B0.x); x1v[0].y = packh2(A1.x, B1.x);
            x1v[1].x = packh2(A0.y, B0.y); x1v[1].y = packh2(A1.y, B1.y);
            x1v[2].x = packh2(A0.z, B0.z); x1v[2].y = packh2(A1.z, B1.z);
            x1v[3].x = packh2(A0.w, B0.w); x1v[3].y = packh2(A1.w, B1.w);
        }
        {   // channels 4..7 (ch-pairs j=2,3)
            const float4 A2 = *reinterpret_cast<const float4*>(p1 + 4 * HW);
            const float4 B2 = *reinterpret_cast<const float4*>(p1 + 5 * HW);
            const float4 A3 = *reinterpret_cast<const float4*>(p1 + 6 * HW);
            const float4 B3 = *reinterpret_cast<const float4*>(p1 + 7 * HW);
            x1v[0].z = packh2(A2.x, B2.x); x1v[0].w = packh2(A3.x, B3.x);
            x1v[1].z = packh2(A2.y, B2.y); x1v[1].w = packh2(A3.y, B3.y);
            x1v[2].z = packh2(A2.z, B2.z); x1v[2].w = packh2(A3.z, B3.z);
            x1v[3].z = packh2(A2.w, B2.w); x1v[3].w = packh2(A3.w, B3.w);
        }
        #pragma unroll
        for (int t = 0; t < 12; ++t) {
            const int ad = (t & 1) ? (a2p[t >> 1] >> 16) : (a2p[t >> 1] & 0xffff);
            const uint4 x2v = *reinterpret_cast<const uint4*>(&S2rd[ad]);
            #pragma unroll
            for (int p = 0; p < 4; ++p) {
                const int dxx = t - p;          // compile-time after unroll
                if (dxx >= 0 && dxx <= 8) {
                    float a = acc[p][dxx];
                    a = dot2(x1v[p].x, x2v.x, a);
                    a = dot2(x1v[p].y, x2v.y, a);
                    a = dot2(x1v[p].z, x2v.z, a);
                    a = dot2(x1v[p].w, x2v.w, a);
                    acc[p][dxx] = a;
                }
            }
        }
    };

    // ---------------- chunk loop: dbuf x2, ONE barrier per chunk ----------
    for (int i = tid; i < 2 * S2SZ; i += NTHR) (&smem[0][0])[i] = 0u;  // pads
    __syncthreads();                  // zeros visible before first stage
    STAGE(0, smem[0]);
    __syncthreads();                  // buf0 ready

    #pragma unroll 1
    for (int cc = 0; cc < NCH; cc += 2) {
        FULL(cc, smem[0], smem[1], true);             // stages cc+1 -> buf1
        __syncthreads();
        FULL(cc + 1, smem[1], smem[0], cc + 2 < NCH); // stages cc+2 -> buf0
        __syncthreads();
    }

    // ---------------- epilogue: mean + leaky_relu + coalesced f32x4 writes -
    const float inv = 1.0f / 256.0f;
    const int dy = 3 * dg + wid;
    float* ob = out + (((size_t)(b * 81 + dy * 9)) * H_ + (h0 + hr)) * W_ + wq * 4;
    #pragma unroll
    for (int dxx = 0; dxx < 9; ++dxx) {
        float4 o;
        float v;
        v = acc[0][dxx] * inv; o.x = v >= 0.f ? v : 0.1f * v;
        v = acc[1][dxx] * inv; o.y = v >= 0.f ? v : 0.1f * v;
        v = acc[2][dxx] * inv; o.z = v >= 0.f ? v : 0.1f * v;
        v = acc[3][dxx] * inv; o.w = v >= 0.f ? v : 0.1f * v;
        *reinterpret_cast<float4*>(ob + (size_t)dxx * HW) = o;
    }
}

extern "C" void kernel_launch(void* const* d_in, const int* in_sizes, int n_in,
                              void* d_out, int out_size, void* d_ws, size_t ws_size,
                              hipStream_t stream) {
    const float* x1 = (const float*)d_in[0];
    const float* x2 = (const float*)d_in[1];
    float* out = (float*)d_out;
    corr_kernel<<<dim3(B_, H_ / TH, 3), dim3(NTHR), 0, stream>>>(x1, x2, out);
}